// Round 6
// baseline (5746.003 us; speedup 1.0000x reference)
//
#include <hip/hip_runtime.h>
#include <hip/hip_fp16.h>
#include <stdint.h>

#define NB   64      // batch
#define NT   2048    // time steps
#define NF   256     // input features
#define NH   256     // hidden
#define NG   768     // 3*NH

typedef unsigned int u32;
typedef _Float16 f16;
typedef f16  f16x2  __attribute__((ext_vector_type(2)));
typedef __fp16 mf16x8 __attribute__((ext_vector_type(8)));   // MFMA operand type
typedef float f32x4 __attribute__((ext_vector_type(4)));
typedef u32   u32x4 __attribute__((ext_vector_type(4)));
typedef f16 half2v __attribute__((ext_vector_type(2)));

__device__ __forceinline__ u32 packpair(float a, float b) {
    return __builtin_bit_cast(u32, __builtin_amdgcn_cvt_pkrtz(a, b));   // v_cvt_pkrtz_f16_f32
}
__device__ __forceinline__ float fdot2u(u32 w, u32 h, float acc) {      // f32-acc dot2
#if __has_builtin(__builtin_amdgcn_fdot2)
    return __builtin_amdgcn_fdot2(__builtin_bit_cast(half2v, w),
                                  __builtin_bit_cast(half2v, h), acc, false);
#else
    half2v wv = __builtin_bit_cast(half2v, w), hv = __builtin_bit_cast(half2v, h);
    return fmaf((float)wv[1], (float)hv[1], fmaf((float)wv[0], (float)hv[0], acc));
#endif
}

// ============ Kernel 1: xi2 = (x @ Wi) + bias(r,z), fragment-layout f16 =====
// Block = 16 batches x 2 timesteps (rows r = b'*2+dt). After the GEMM,
// results are restaged in LDS into the gru_rec consumer layout:
//   f16 idx = (B16*NT + t)*12288 + w*1536 + l*24 + reg*6 + tile*3 + g
// (w=u>>5, tile=(u>>4)&1, l=(u&15)|((b'>>2)<<4), reg=b'&3), then stored with
// fully-coalesced 4KB-contiguous uint4 stores. r/z biases folded in here.
__global__ __launch_bounds__(256, 2) void xi_gemm(const float* __restrict__ x,
                                                  const float* __restrict__ Wi,
                                                  const float* __restrict__ bh,
                                                  f16* __restrict__ xi2) {
    __shared__ u32 xs2[32][128];                 // packed f16 pairs of x rows
    __shared__ __align__(16) f16 stage[24576];   // 48KB restage buffer
    const int tid = threadIdx.x;
    const int B16 = blockIdx.x >> 10;            // batch group 0..3
    const int t0  = (blockIdx.x & 1023) * 2;     // 2 timesteps per block

    {
        const int hi = tid >> 7, lo = tid & 127;
        #pragma unroll
        for (int rr = 0; rr < 16; ++rr) {
            const int r  = rr * 2 + hi;
            const int bp = r >> 1, dt = r & 1;
            const size_t grow = (size_t)(B16 * 16 + bp) * NT + t0 + dt;
            const float2 v = *(const float2*)&x[grow * NF + lo * 2];
            xs2[r][lo] = packpair(v.x, v.y);
        }
    }
    __syncthreads();

    float acc[32][3];
    #pragma unroll
    for (int r = 0; r < 32; ++r) { acc[r][0] = 0.f; acc[r][1] = 0.f; acc[r][2] = 0.f; }

    for (int kp2 = 0; kp2 < 64; ++kp2) {         // 4 K-rows per iteration
        const int k = kp2 * 4;
        u32 wA[3], wB[3];
        #pragma unroll
        for (int j = 0; j < 3; ++j) {
            const float* wp = &Wi[(size_t)k * NG + j * 256 + tid];
            wA[j] = packpair(wp[0],              wp[NG]);
            wB[j] = packpair(wp[2 * (size_t)NG], wp[3 * (size_t)NG]);
        }
        #pragma unroll
        for (int r = 0; r < 32; ++r) {
            const uint2 xv = *(const uint2*)&xs2[r][kp2 * 2];   // uniform broadcast
            #pragma unroll
            for (int j = 0; j < 3; ++j)
                acc[r][j] = fdot2u(wB[j], xv.y, fdot2u(wA[j], xv.x, acc[r][j]));
        }
    }

    // restage into consumer-fragment layout (fold r,z biases; n-bias NOT folded)
    const float b0 = bh[tid], b1 = bh[256 + tid];
    {
        const int u = tid, w = u >> 5, tile = (u >> 4) & 1, lane_lo = u & 15;
        #pragma unroll
        for (int r = 0; r < 32; ++r) {
            const int bp = r >> 1, dt = r & 1;
            const int l  = lane_lo | ((bp >> 2) << 4);
            const int reg = bp & 3;
            const int base = dt * 12288 + w * 1536 + l * 24 + reg * 6 + tile * 3;
            stage[base + 0] = (f16)(acc[r][0] + b0);
            stage[base + 1] = (f16)(acc[r][1] + b1);
            stage[base + 2] = (f16)(acc[r][2]);
        }
    }
    __syncthreads();

    // coalesced copy out: 48KB contiguous
    const u32x4* src = (const u32x4*)stage;
    u32x4* dst = (u32x4*)(xi2 + ((size_t)B16 * NT + t0) * 12288);
    #pragma unroll
    for (int i = 0; i < 12; ++i)
        dst[i * 256 + tid] = src[i * 256 + tid];
}

// ============ Kernel 2: MFMA recurrent scan — 4 blocks x 16 batches ========
// 512 threads = 8 waves; wave w owns output cols [w*32, w*32+32) x 3 gates.
// B (Wh) = 48 fragment-tiles/wave = 192 u32, loop-invariant (AGPR-friendly:
// MFMA reads AGPR operands natively on gfx950). A (=h, [16,256] f16) lives
// in LDS in FRAGMENT ORDER (addr = kk*1024 + lane*16 bytes) -> conflict-free
// ds_read_b128; double-buffered -> ONE barrier/step. Gates computed in
// C-fragment registers (col=lane&15, row=(lane>>4)*4+reg). xi prefetched
// with global_load_lds (zero VGPRs).
__global__ __launch_bounds__(512, 2) void gru_rec(
        const float* __restrict__ carry,
        const f16*   __restrict__ xi2,
        const float* __restrict__ Wh,
        const float* __restrict__ bh,
        float* __restrict__ out_carry,
        float* __restrict__ out_hidden) {
    __shared__ __align__(16) f16 A_lds[2][4096];     // 2 x 8KB
    __shared__ __align__(16) f16 XI_lds[2][12288];   // 2 x 24KB

    const int tid = threadIdx.x;
    const int B16 = blockIdx.x;          // 0..3
    const int w   = tid >> 6;            // wave 0..7
    const int l   = tid & 63;
    const int lane_lo = l & 15;
    const int lgrp    = l >> 4;          // 0..3
    const int c0 = w * 32;

    // ---- B fragments (Wh), packed f16, loop-invariant
    u32x4 bfr[2][3][8];
    #pragma unroll
    for (int tile = 0; tile < 2; ++tile)
      #pragma unroll
      for (int g = 0; g < 3; ++g)
        #pragma unroll
        for (int kk = 0; kk < 8; ++kk) {
            const float* wp = &Wh[(size_t)(kk * 32 + lgrp * 8) * NG + g * 256 + c0 + tile * 16 + lane_lo];
            u32x4 bv;
            #pragma unroll
            for (int jj = 0; jj < 4; ++jj)
                bv[jj] = packpair(wp[(size_t)(2 * jj) * NG], wp[(size_t)(2 * jj + 1) * NG]);
            bfr[tile][g][kk] = bv;
        }

    const float bn0 = bh[512 + c0 + lane_lo];
    const float bn1 = bh[512 + c0 + 16 + lane_lo];

    // ---- h_prev (f32, C-fragment positions) + initial A buffer
    float hp[2][4];
    #pragma unroll
    for (int tile = 0; tile < 2; ++tile)
      #pragma unroll
      for (int reg = 0; reg < 4; ++reg) {
        const int bp = lgrp * 4 + reg;
        const int u  = c0 + tile * 16 + lane_lo;
        hp[tile][reg] = carry[(size_t)(B16 * 16 + bp) * NH + u];
        A_lds[0][w * 512 + (bp + (tile * 2 + (lane_lo >> 3)) * 16) * 8 + (lane_lo & 7)] = (f16)hp[tile][reg];
      }

    // ---- xi prefetch for t=0
    {
        const f16* src = xi2 + ((size_t)(B16 * NT + 0) * 8 + w) * 1536 + l * 24;
        #pragma unroll
        for (int p = 0; p < 3; ++p)
            __builtin_amdgcn_global_load_lds((const u32*)(src + p * 8),
                                             (u32*)&XI_lds[0][w * 1536 + p * 512], 16, 0, 0);
    }
    __syncthreads();

    for (int t = 0; t < NT; ++t) {
        const int cur = t & 1, nxt = cur ^ 1;

        // issue next step's xi loads (land by the end-of-step barrier)
        if (t + 1 < NT) {
            const f16* src = xi2 + ((size_t)(B16 * NT + (t + 1)) * 8 + w) * 1536 + l * 24;
            #pragma unroll
            for (int p = 0; p < 3; ++p)
                __builtin_amdgcn_global_load_lds((const u32*)(src + p * 8),
                                                 (u32*)&XI_lds[nxt][w * 1536 + p * 512], 16, 0, 0);
        }

        // ---- GEMV via MFMA: acc[tile][g] = H @ Wh-slice
        f32x4 acc[2][3];
        #pragma unroll
        for (int tile = 0; tile < 2; ++tile)
            #pragma unroll
            for (int g = 0; g < 3; ++g)
                acc[tile][g] = (f32x4){0.f, 0.f, 0.f, 0.f};

        const char* Abase = (const char*)&A_lds[cur][0] + l * 16;
        u32x4 aC = *(const u32x4*)(Abase);
        #pragma unroll
        for (int kk = 0; kk < 8; ++kk) {
            u32x4 aN = aC;
            if (kk < 7) aN = *(const u32x4*)(Abase + (kk + 1) * 1024);
            const mf16x8 av = __builtin_bit_cast(mf16x8, aC);
            #pragma unroll
            for (int tile = 0; tile < 2; ++tile)
                #pragma unroll
                for (int g = 0; g < 3; ++g)
                    acc[tile][g] = __builtin_amdgcn_mfma_f32_16x16x32_f16(
                        av, __builtin_bit_cast(mf16x8, bfr[tile][g][kk]), acc[tile][g], 0, 0, 0);
            aC = aN;
        }

        // ---- current xi (resident since last barrier)
        u32 xw[12];
        #pragma unroll
        for (int p = 0; p < 3; ++p) {
            const u32x4 v = *(const u32x4*)&XI_lds[cur][w * 1536 + p * 512 + l * 8];
            xw[p * 4 + 0] = v[0]; xw[p * 4 + 1] = v[1];
            xw[p * 4 + 2] = v[2]; xw[p * 4 + 3] = v[3];
        }
#define XHALF(q) ((float)(__builtin_bit_cast(f16x2, xw[(q) >> 1])[(q) & 1]))

        // ---- gates in C-fragment registers
        #pragma unroll
        for (int tile = 0; tile < 2; ++tile) {
            const float bnv = tile ? bn1 : bn0;
            #pragma unroll
            for (int reg = 0; reg < 4; ++reg) {
                const int q0 = reg * 6 + tile * 3;
                const float sr  = acc[tile][0][reg] + XHALF(q0 + 0);   // r/z bias pre-folded
                const float sz  = acc[tile][1][reg] + XHALF(q0 + 1);
                const float hpn = acc[tile][2][reg] + bnv;
                const float xn  = XHALF(q0 + 2);
                const float rg = __builtin_amdgcn_rcpf(1.f + __expf(-sr));
                const float zg = __builtin_amdgcn_rcpf(1.f + __expf(-sz));
                const float tt = xn + rg * hpn;
                const float ng = 1.f - 2.f * __builtin_amdgcn_rcpf(1.f + __expf(2.f * tt));
                const float hn = ng + zg * (hp[tile][reg] - ng);
                hp[tile][reg] = hn;
                const int bp = lgrp * 4 + reg;
                const int u  = c0 + tile * 16 + lane_lo;
                out_hidden[((size_t)(B16 * 16 + bp) * NT + t) * NH + u] = hn;
                A_lds[nxt][w * 512 + (bp + (tile * 2 + (lane_lo >> 3)) * 16) * 8 + (lane_lo & 7)] = (f16)hn;
            }
        }
#undef XHALF
        __syncthreads();   // drains vmcnt (xi loads) + lgkm (A writes)
    }

    #pragma unroll
    for (int tile = 0; tile < 2; ++tile)
        #pragma unroll
        for (int reg = 0; reg < 4; ++reg) {
            const int bp = lgrp * 4 + reg;
            const int u  = c0 + tile * 16 + lane_lo;
            out_carry[(size_t)(B16 * 16 + bp) * NH + u] = hp[tile][reg];
        }
}

// ================= host =================
extern "C" void kernel_launch(void* const* d_in, const int* in_sizes, int n_in,
                              void* d_out, int out_size, void* d_ws, size_t ws_size,
                              hipStream_t stream) {
    const float* carry = (const float*)d_in[0];
    const float* x     = (const float*)d_in[1];
    const float* Wi    = (const float*)d_in[2];
    const float* Wh    = (const float*)d_in[3];
    const float* bh    = (const float*)d_in[4];

    float* out_carry  = (float*)d_out;
    float* out_hidden = out_carry + (size_t)NB * NH;

    f16* xi2 = (f16*)d_ws;   // 64*2048*768*2 B = 201.3 MB

    xi_gemm<<<dim3(4096), dim3(256), 0, stream>>>(x, Wi, bh, xi2);
    gru_rec<<<dim3(4), dim3(512), 0, stream>>>(carry, xi2, Wh, bh,
                                               out_carry, out_hidden);
}

// Round 7
// 3419.533 us; speedup vs baseline: 1.6803x; 1.6803x over previous
//
#include <hip/hip_runtime.h>
#include <hip/hip_fp16.h>
#include <stdint.h>

#define NB   64      // batch
#define NT   2048    // time steps
#define NF   256     // input features
#define NH   256     // hidden
#define NG   768     // 3*NH

typedef unsigned int u32;
typedef _Float16 f16;
typedef f16 half2v __attribute__((ext_vector_type(2)));

__device__ __forceinline__ u32 packpair(float a, float b) {
    return __builtin_bit_cast(u32, __builtin_amdgcn_cvt_pkrtz(a, b));   // v_cvt_pkrtz_f16_f32
}
__device__ __forceinline__ float fdot2u(u32 w, u32 h, float acc) {      // f32-acc dot2
#if __has_builtin(__builtin_amdgcn_fdot2)
    return __builtin_amdgcn_fdot2(__builtin_bit_cast(half2v, w),
                                  __builtin_bit_cast(half2v, h), acc, false);
#else
    half2v wv = __builtin_bit_cast(half2v, w), hv = __builtin_bit_cast(half2v, h);
    return fmaf((float)wv[1], (float)hv[1], fmaf((float)wv[0], (float)hv[0], acc));
#endif
}
__device__ __forceinline__ u32 hfma2u(u32 w, u32 h, u32 acc) {          // v_pk_fma_f16
    __half2 r = __hfma2(__builtin_bit_cast(__half2, w),
                        __builtin_bit_cast(__half2, h),
                        __builtin_bit_cast(__half2, acc));
    return __builtin_bit_cast(u32, r);
}
__device__ __forceinline__ float pairsum(u32 a) {
    __half2 h = __builtin_bit_cast(__half2, a);
    return __low2float(h) + __high2float(h);
}
// sum across the 4 lanes of a quad — 2 DPP adds
__device__ __forceinline__ float quad_sum(float v) {
    int i = __builtin_bit_cast(int, v);
    v += __builtin_bit_cast(float, __builtin_amdgcn_update_dpp(0, i, 0xB1, 0xF, 0xF, true)); // [1,0,3,2]
    i = __builtin_bit_cast(int, v);
    v += __builtin_bit_cast(float, __builtin_amdgcn_update_dpp(0, i, 0x4E, 0xF, 0xF, true)); // [2,3,0,1]
    return v;
}

// ================= Kernel 1: xi = x @ Wi  (round-3 proven: fdot2, f32 acc) ==
__global__ __launch_bounds__(256, 2) void xi_gemm(const float* __restrict__ x,
                                                  const float* __restrict__ Wi,
                                                  __half* __restrict__ xi) {
    __shared__ u32 xs2[32][128];           // xs2[r][p] = (x[r][2p], x[r][2p+1]) f16
    const int tid = threadIdx.x;
    const int r0  = blockIdx.x * 32;
    {
        const int hi = tid >> 7, lo = tid & 127;
        #pragma unroll
        for (int rr = 0; rr < 16; ++rr) {
            const int r = rr * 2 + hi;
            const float2 v = *(const float2*)&x[(size_t)(r0 + r) * NF + lo * 2];
            xs2[r][lo] = packpair(v.x, v.y);
        }
    }
    __syncthreads();

    float acc[32][3];
    #pragma unroll
    for (int r = 0; r < 32; ++r) { acc[r][0] = 0.f; acc[r][1] = 0.f; acc[r][2] = 0.f; }

    for (int kp2 = 0; kp2 < 64; ++kp2) {   // 4 K-rows per iteration
        const int k = kp2 * 4;
        u32 wA[3], wB[3];
        #pragma unroll
        for (int j = 0; j < 3; ++j) {
            const float* wp = &Wi[(size_t)k * NG + j * 256 + tid];
            wA[j] = packpair(wp[0],              wp[NG]);
            wB[j] = packpair(wp[2 * (size_t)NG], wp[3 * (size_t)NG]);
        }
        #pragma unroll
        for (int r = 0; r < 32; ++r) {
            const uint2 xv = *(const uint2*)&xs2[r][kp2 * 2];   // uniform -> broadcast
            #pragma unroll
            for (int j = 0; j < 3; ++j)
                acc[r][j] = fdot2u(wB[j], xv.y, fdot2u(wA[j], xv.x, acc[r][j]));
        }
    }

    #pragma unroll
    for (int r = 0; r < 32; ++r)
        #pragma unroll
        for (int j = 0; j < 3; ++j)
            xi[(size_t)(r0 + r) * NG + j * 256 + tid] = __float2half(acc[r][j]);
}

// ================= Kernel 2: recurrent scan — ONE block per batch ==========
// 512 threads = (u2 in [0,128), kc = tid&3). Thread owns units {u2, u2+128}
// x 3 gates over k-chunk [64kc, 64kc+64): 192 packed-f16 Wh u32.
// __launch_bounds__(512, 1): 8 waves/CU -> 256-VGPR budget so wh2 stays
// ARCHITECTURAL. (512,2) was the rounds-4/5 bug: 16 waves -> 128-VGPR cap
// -> forced AGPR shadowing of the weight array (VGPR_Count=128 signature).
// Quad reduce = 2 DPP adds; gates in-register; double-buffered h replicas
// -> ONE barrier/step.
__global__ __launch_bounds__(512, 1) void gru_rec(
        const float* __restrict__ carry,
        const __half* __restrict__ xi,
        const float* __restrict__ Wh,
        const float* __restrict__ bh,
        float* __restrict__ out_carry,
        float* __restrict__ out_hidden) {
    __shared__ u32 hsh[2][4][136];     // [buf][replica][128 pairs + pad]

    const int tid = threadIdx.x;
    const int b   = blockIdx.x;
    const int u2  = tid >> 2;          // 0..127 ; owns units u2 and u2+128
    const int kc  = tid & 3;           // k-chunk 0..3
    const int k0  = kc * 64;

    // ---- register-stationary Wh: wh2[uu][j][p] = packed (k0+2p, k0+2p+1)
    u32 wh2[2][3][32];
    #pragma unroll
    for (int uu = 0; uu < 2; ++uu)
        #pragma unroll
        for (int j = 0; j < 3; ++j) {
            const float* wp = &Wh[(size_t)k0 * NG + j * 256 + uu * 128 + u2];
            #pragma unroll
            for (int p = 0; p < 32; ++p) {
                wh2[uu][j][p] = packpair(wp[0], wp[NG]);
                wp += 2 * (size_t)NG;
            }
        }
    const float br0 = bh[u2],       bz0 = bh[256 + u2],       bn0 = bh[512 + u2];
    const float br1 = bh[128 + u2], bz1 = bh[384 + u2], bn1 = bh[640 + u2];

    float h0reg = carry[(size_t)b * NH + u2];
    float h1reg = carry[(size_t)b * NH + 128 + u2];
    ((__half*)&hsh[0][kc][0])[u2]       = __float2half(h0reg);
    ((__half*)&hsh[0][kc][0])[128 + u2] = __float2half(h1reg);

    const __half* xp = xi + (size_t)b * NT * NG;
    __half xr0 = xp[u2],       xz0 = xp[256 + u2],       xn0 = xp[512 + u2];
    __half xr1 = xp[128 + u2], xz1 = xp[384 + u2], xn1 = xp[640 + u2];
    const __half* xq = xp + NG;                 // prefetch cursor (t+1)

    __syncthreads();

#define FMA6(p, hc) { a00 = hfma2u(wh2[0][0][p], hc, a00);  \
                      a01 = hfma2u(wh2[0][1][p], hc, a01);  \
                      a02 = hfma2u(wh2[0][2][p], hc, a02);  \
                      a10 = hfma2u(wh2[1][0][p], hc, a10);  \
                      a11 = hfma2u(wh2[1][1][p], hc, a11);  \
                      a12 = hfma2u(wh2[1][2][p], hc, a12); }

    for (int t = 0; t < NT; ++t) {
        const uint4* hp4 = (const uint4*)&hsh[t & 1][kc][kc * 32];
        u32 a00 = 0, a01 = 0, a02 = 0, a10 = 0, a11 = 0, a12 = 0;
        #pragma unroll
        for (int ph = 0; ph < 4; ++ph) {        // 4 phases x 8 pairs: caps live h regs
            const uint4 hA = hp4[2 * ph], hB = hp4[2 * ph + 1];
            FMA6(8 * ph + 0, hA.x); FMA6(8 * ph + 1, hA.y);
            FMA6(8 * ph + 2, hA.z); FMA6(8 * ph + 3, hA.w);
            FMA6(8 * ph + 4, hB.x); FMA6(8 * ph + 5, hB.y);
            FMA6(8 * ph + 6, hB.z); FMA6(8 * ph + 7, hB.w);
            asm volatile("" ::: "memory");
        }
        const float s00 = quad_sum(pairsum(a00));
        const float s01 = quad_sum(pairsum(a01));
        const float s02 = quad_sum(pairsum(a02));
        const float s10 = quad_sum(pairsum(a10));
        const float s11 = quad_sum(pairsum(a11));
        const float s12 = quad_sum(pairsum(a12));

        // gates (all 4 quad lanes redundantly -> identical f32 results)
        const float rg0 = 1.f / (1.f + __expf(-(__half2float(xr0) + s00 + br0)));
        const float zg0 = 1.f / (1.f + __expf(-(__half2float(xz0) + s01 + bz0)));
        const float tt0 = __half2float(xn0) + rg0 * (s02 + bn0);
        const float ng0 = 1.f - 2.f / (__expf(2.f * tt0) + 1.f);
        const float hn0 = (1.f - zg0) * ng0 + zg0 * h0reg;
        const float rg1 = 1.f / (1.f + __expf(-(__half2float(xr1) + s10 + br1)));
        const float zg1 = 1.f / (1.f + __expf(-(__half2float(xz1) + s11 + bz1)));
        const float tt1 = __half2float(xn1) + rg1 * (s12 + bn1);
        const float ng1 = 1.f - 2.f / (__expf(2.f * tt1) + 1.f);
        const float hn1 = (1.f - zg1) * ng1 + zg1 * h1reg;
        h0reg = hn0; h1reg = hn1;

        if (kc == 0) {
            float* o = out_hidden + ((size_t)b * NT + t) * NH + u2;
            o[0] = hn0; o[128] = hn1;
        }
        ((__half*)&hsh[(t + 1) & 1][kc][0])[u2]       = __float2half(hn0);
        ((__half*)&hsh[(t + 1) & 1][kc][0])[128 + u2] = __float2half(hn1);

        if (t + 1 < NT) {                      // prefetch next xi
            xr0 = xq[u2];       xz0 = xq[256 + u2];       xn0 = xq[512 + u2];
            xr1 = xq[128 + u2]; xz1 = xq[384 + u2]; xn1 = xq[640 + u2];
            xq += NG;
        }
        __syncthreads();
    }
#undef FMA6

    if (kc == 0) {
        out_carry[(size_t)b * NH + u2]       = h0reg;
        out_carry[(size_t)b * NH + 128 + u2] = h1reg;
    }
}

// ================= host =================
extern "C" void kernel_launch(void* const* d_in, const int* in_sizes, int n_in,
                              void* d_out, int out_size, void* d_ws, size_t ws_size,
                              hipStream_t stream) {
    const float* carry = (const float*)d_in[0];
    const float* x     = (const float*)d_in[1];
    const float* Wi    = (const float*)d_in[2];
    const float* Wh    = (const float*)d_in[3];
    const float* bh    = (const float*)d_in[4];

    float* out_carry  = (float*)d_out;
    float* out_hidden = out_carry + (size_t)NB * NH;

    __half* xi = (__half*)d_ws;   // 64*2048*768*2 B = 201.3 MB (fits, proven)

    xi_gemm<<<dim3(NB * NT / 32), dim3(256), 0, stream>>>(x, Wi, xi);
    gru_rec<<<dim3(NB), dim3(512), 0, stream>>>(carry, xi, Wh, bh,
                                                out_carry, out_hidden);
}